// Round 3
// baseline (261.154 us; speedup 1.0000x reference)
//
#include <hip/hip_runtime.h>

// Problem constants
#define BB      8
#define DIMD    1024
#define NTOK    4096
#define CC      6
#define TN      64            // n-columns per block tile
#define NWAVE   8             // waves per block
#define NTHREADS (NWAVE * 64) // 512
#define RPW     (DIMD / NWAVE) // 128 d-rows per wave

__global__ __launch_bounds__(NTHREADS, 4)   // 4 waves/EU -> 16 waves/CU -> 2 blocks/CU
void lq_fused(const float* __restrict__ z,  const float* __restrict__ Wi,
              const float* __restrict__ bi, const float* __restrict__ Wo,
              const float* __restrict__ bo, float* __restrict__ out,
              float* __restrict__ idx_out,  float* __restrict__ loss_out)
{
    // weight table: per d-row 12 floats {wi0..5, wo0..5} packed as 3 x float4 (48B stride,
    // 16B-aligned -> ds_read_b128, wave-uniform broadcast) + bo separately.
    __shared__ float4 wt[DIMD][3];   // 48 KB
    __shared__ float  bol[DIMD];     // 4 KB
    __shared__ float  acc[TN][15];   // 3.75 KB, stride 15 (odd) -> conflict-free atomics
    __shared__ float  qs[CC][TN];    // 1.5 KB
    __shared__ float  redw[NWAVE];

    const int t    = threadIdx.x;
    const int lane = t & 63;
    const int wv   = t >> 6;
    const int blk  = blockIdx.x;
    const int b    = blk >> 6;          // 64 n-tiles per batch
    const int n0   = (blk & 63) << 6;   // * TN

    // ---------------- stage weights to LDS (coalesced along d) --------------------
    for (int d = t; d < DIMD; d += NTHREADS) {
        float i0 = Wi[0 * DIMD + d], i1 = Wi[1 * DIMD + d], i2 = Wi[2 * DIMD + d];
        float i3 = Wi[3 * DIMD + d], i4 = Wi[4 * DIMD + d], i5 = Wi[5 * DIMD + d];
        const float* wr = Wo + d * CC;
        float o0 = wr[0], o1 = wr[1], o2 = wr[2], o3 = wr[3], o4 = wr[4], o5 = wr[5];
        wt[d][0] = make_float4(i0, i1, i2, i3);
        wt[d][1] = make_float4(i4, i5, o0, o1);
        wt[d][2] = make_float4(o2, o3, o4, o5);
        bol[d]   = bo[d];
    }
    for (int i = t; i < TN * 15; i += NTHREADS) ((float*)acc)[i] = 0.f;
    __syncthreads();

    const int dbase = wv * RPW;
    const size_t zoff = ((size_t)b * DIMD + (size_t)dbase) * NTOK + (size_t)n0 + (size_t)lane;
    const float* zp = z + zoff;

    // ---------------- pass 1: accumulate x (Wi.z), y (Wo^T.z), bo.z, z.z ----------
    float xa0 = 0.f, xa1 = 0.f, xa2 = 0.f, xa3 = 0.f, xa4 = 0.f, xa5 = 0.f;
    float ya0 = 0.f, ya1 = 0.f, ya2 = 0.f, ya3 = 0.f, ya4 = 0.f, ya5 = 0.f;
    float zbp = 0.f, zzp = 0.f;

    #pragma unroll 4
    for (int i = 0; i < RPW; ++i) {
        const float zv = zp[(size_t)i * NTOK];   // coalesced 256B/wave-instr
        const int d = dbase + i;                 // wave-uniform -> broadcast LDS reads
        const float4 wA = wt[d][0];
        const float4 wB = wt[d][1];
        const float4 wC = wt[d][2];
        const float  bv = bol[d];
        xa0 = fmaf(zv, wA.x, xa0); xa1 = fmaf(zv, wA.y, xa1);
        xa2 = fmaf(zv, wA.z, xa2); xa3 = fmaf(zv, wA.w, xa3);
        xa4 = fmaf(zv, wB.x, xa4); xa5 = fmaf(zv, wB.y, xa5);
        ya0 = fmaf(zv, wB.z, ya0); ya1 = fmaf(zv, wB.w, ya1);
        ya2 = fmaf(zv, wC.x, ya2); ya3 = fmaf(zv, wC.y, ya3);
        ya4 = fmaf(zv, wC.z, ya4); ya5 = fmaf(zv, wC.w, ya5);
        zbp = fmaf(zv, bv, zbp);
        zzp = fmaf(zv, zv, zzp);
    }

    // fold wave partials into per-column accumulators (LDS f32 atomics, one-time)
    {
        float* a = acc[lane];
        atomicAdd(&a[0],  xa0); atomicAdd(&a[1],  xa1); atomicAdd(&a[2],  xa2);
        atomicAdd(&a[3],  xa3); atomicAdd(&a[4],  xa4); atomicAdd(&a[5],  xa5);
        atomicAdd(&a[6],  ya0); atomicAdd(&a[7],  ya1); atomicAdd(&a[8],  ya2);
        atomicAdd(&a[9],  ya3); atomicAdd(&a[10], ya4); atomicAdd(&a[11], ya5);
        atomicAdd(&a[12], zbp); atomicAdd(&a[13], zzp);
    }
    __syncthreads();

    // ---------------- finalize + quantize (one thread per n-column, wave 0) --------
    float lossA = 0.f;
    if (t < TN) {
        const float* pr = acc[t];
        float X0 = bi[0] + pr[0], X1 = bi[1] + pr[1], X2 = bi[2] + pr[2];
        float X3 = bi[3] + pr[3], X4 = bi[4] + pr[4], X5 = bi[5] + pr[5];
        float Y0 = pr[6], Y1 = pr[7], Y2 = pr[8], Y3 = pr[9], Y4 = pr[10], Y5 = pr[11];
        float ZB = pr[12], ZZ = pr[13];

        float idxf  = 0.f;
        float cross = ZB;
        float basis = 1.f;
        #define QSTEP(Xc, Yc, cidx)                                             \
        {                                                                       \
            float lv = rintf(fmaf((Xc), 8.f, 4.f));                             \
            lv = fminf(fmaxf(lv, 0.f), 7.f);                                    \
            float q = fmaf(lv, 0.125f, -0.5f);                                  \
            qs[cidx][t] = q;                                                    \
            cross = fmaf(q, (Yc), cross);                                       \
            idxf  = fmaf(lv, basis, idxf);                                      \
            basis *= 8.f;                                                       \
        }
        QSTEP(X0, Y0, 0) QSTEP(X1, Y1, 1) QSTEP(X2, Y2, 2)
        QSTEP(X3, Y3, 3) QSTEP(X4, Y4, 4) QSTEP(X5, Y5, 5)
        #undef QSTEP

        idx_out[b * NTOK + n0 + t] = idxf;        // integer-valued float, exact (< 2^24)
        lossA = ZZ - 2.f * cross;                 // sum z^2 - 2 sum out*z (this column)
        #pragma unroll
        for (int o = 32; o; o >>= 1) lossA += __shfl_down(lossA, o); // wave 0 only
    }
    __syncthreads();

    // ---------------- pass 2: out = Wo.q + bo, accumulate sum out^2 ----------------
    const float qv0 = qs[0][lane], qv1 = qs[1][lane], qv2 = qs[2][lane];
    const float qv3 = qs[3][lane], qv4 = qs[4][lane], qv5 = qs[5][lane];

    float lossB = 0.f;
    float* op = out + zoff;
    #pragma unroll 4
    for (int i = 0; i < RPW; ++i) {
        const int d = dbase + i;
        const float4 wB = wt[d][1];
        const float4 wC = wt[d][2];
        float o = bol[d];
        o = fmaf(qv0, wB.z, o);
        o = fmaf(qv1, wB.w, o);
        o = fmaf(qv2, wC.x, o);
        o = fmaf(qv3, wC.y, o);
        o = fmaf(qv4, wC.z, o);
        o = fmaf(qv5, wC.w, o);
        op[(size_t)i * NTOK] = o;                 // coalesced 256B/wave-instr
        lossB = fmaf(o, o, lossB);
    }
    #pragma unroll
    for (int o = 32; o; o >>= 1) lossB += __shfl_down(lossB, o);
    if (lane == 0) redw[wv] = lossB;
    __syncthreads();

    if (t == 0) {
        float s = lossA;                           // reduced wave-0 value (lane 0)
        #pragma unroll
        for (int w = 0; w < NWAVE; ++w) s += redw[w];
        atomicAdd(loss_out, s * (0.2f / 33554432.f));
    }
}

extern "C" void kernel_launch(void* const* d_in, const int* in_sizes, int n_in,
                              void* d_out, int out_size, void* d_ws, size_t ws_size,
                              hipStream_t stream) {
    const float* z  = (const float*)d_in[0];
    const float* Wi = (const float*)d_in[1];
    const float* bi = (const float*)d_in[2];
    const float* Wo = (const float*)d_in[3];
    const float* bo = (const float*)d_in[4];
    // d_in[5] = vals (uniform levels l/8 - 0.5) -- encoded analytically in the kernel

    float* out   = (float*)d_out;
    float* idxp  = out + (size_t)BB * DIMD * NTOK;   // 33554432
    float* lossp = idxp + (size_t)BB * NTOK;         // +32768

    // zero the loss accumulator (graph-capture-safe async memset on stream)
    hipMemsetAsync(lossp, 0, sizeof(float), stream);

    dim3 grid(BB * (NTOK / TN));   // 512 blocks
    lq_fused<<<grid, NTHREADS, 0, stream>>>(z, Wi, bi, Wo, bo, out, idxp, lossp);
}